// Round 10
// baseline (350.682 us; speedup 1.0000x reference)
//
#include <hip/hip_runtime.h>

// GAT_gate: B=8, N=2048, D=128
// out = c*x + (1-c)*relu(att@h), att = colsoftmax(mask(hA h^T + h hA^T))*adj
// e small (|e|<~6) -> exp without max-subtraction (clamp 60).
// cat[n][0:128]=hA[n], cat[n][128:256]=h[n]; e[i,j] = cat[i] . catsw[j].
// R10 = R9 passing base + k3 occupancy fix:
//  - k3: j-split x4 (R2-proven partial pattern): 2048 blocks (4 resident/CU),
//    raw f32 partial h' sums to out + 3 ws buffers; k4 sums/relu/gate/blend.
//    (R9 analysis: k3 was ~110us at 2 blocks/CU, latency-bound on the
//    GLL->barrier drain; traffic+compute floor is ~30us.)
//  - k2: j-span 256/block (grid 1024, brg amortized), launch_bounds(256,4).
// k2 keeps LDS cat staging (R8: no-LDS regressed). K-split-within-block k3'
// (R5-R7) remains abandoned (proven buggy by R8 bisect).

#define B_ 8
#define N_ 2048
#define D_ 128

typedef __attribute__((ext_vector_type(8))) short short8;
typedef __attribute__((ext_vector_type(4))) float f32x4;

#define GLL(gp, lp) __builtin_amdgcn_global_load_lds( \
    (__attribute__((address_space(1))) const unsigned int*)(gp), \
    (__attribute__((address_space(3))) unsigned int*)(lp), 16, 0, 0)

static __device__ __forceinline__ unsigned short f2bf(float f) {
  union { float f; unsigned int u; } v; v.f = f;
  unsigned int r = v.u + 0x7fffu + ((v.u >> 16) & 1u);
  return (unsigned short)(r >> 16);
}
static __device__ __forceinline__ float bf2f(unsigned short u) {
  union { unsigned int u; float f; } v; v.u = ((unsigned int)u) << 16;
  return v.f;
}

// ---- workspace layout (bytes) ----
#define CAT_OFF  ((size_t)0)         // bf16 cat [B][N][256]        8 MB
#define VT_OFF   ((size_t)8388608)   // bf16 V'^T [B][128][N]       4 MB
#define PUN_OFF  ((size_t)12582912)  // bf16 P_un [B][N][N]         67.1 MB
#define S_OFF    ((size_t)79691776)  // f32 colsum s [B][N]         64 KB
#define WB_OFF   ((size_t)79757312)  // bf16 W [128][128]           32 KB
#define AT_OFF   ((size_t)79790080)  // bf16 A^T [128][128]         32 KB
#define BITS_OFF ((size_t)79822848)  // adj bits [B][N][N/32]       4 MB
#define PART_OFF ((size_t)84017152)  // f32 partials 3 x 8 MB
#define PART_SZ  ((size_t)8388608)

// ---------- prep: W -> bf16 (same layout), A -> bf16 transposed ----------
__global__ void k_cvt(const float* __restrict__ W, const float* __restrict__ A,
                      unsigned short* __restrict__ Wb1, unsigned short* __restrict__ Abt) {
  int t = threadIdx.x;
  for (int i = t; i < 128 * 128; i += 256) {
    Wb1[i] = f2bf(W[i]);
    Abt[(i & 127) * 128 + (i >> 7)] = f2bf(A[i]);
  }
}

// ---------- k_bits2: adj -> bitmask, 32 contiguous elems/thread ----------
__global__ __launch_bounds__(256) void k_bits2(const float* __restrict__ adj,
                                               unsigned int* __restrict__ bits) {
  size_t tid = (size_t)blockIdx.x * 256 + threadIdx.x;
  const float* p = adj + tid * 32;
  unsigned int m = 0;
#pragma unroll
  for (int i = 0; i < 8; i++) {
    f32x4 v = *(const f32x4*)(p + i * 4);
    m |= (v[0] > 0.f ? 1u : 0u) << (i * 4 + 0);
    m |= (v[1] > 0.f ? 1u : 0u) << (i * 4 + 1);
    m |= (v[2] > 0.f ? 1u : 0u) << (i * 4 + 2);
    m |= (v[3] > 0.f ? 1u : 0u) << (i * 4 + 3);
  }
  bits[tid] = m;
}

// ---------- k1: h = x@W^T + b, hA = h@A via MFMA; write cat bf16 ----------
__global__ __launch_bounds__(256) void k1(const float* __restrict__ x,
                                          const unsigned short* __restrict__ Wb1,
                                          const float* __restrict__ Wbias,
                                          const unsigned short* __restrict__ Abt,
                                          unsigned short* __restrict__ cat) {
  __shared__ unsigned short hsm[4][16][136];   // 272 B rows, 16B-aligned
  __shared__ unsigned short hasm[4][16][136];
  const int t = threadIdx.x, w = t >> 6, lane = t & 63;
  const int q = lane >> 4, l15 = lane & 15;
  const size_t r0 = (size_t)blockIdx.x * 64 + w * 16;

  f32x4 acc[8];
#pragma unroll
  for (int dg = 0; dg < 8; dg++) acc[dg] = (f32x4){0.f, 0.f, 0.f, 0.f};
#pragma unroll
  for (int k = 0; k < 4; k++) {
    const float* xp = x + (r0 + l15) * 128 + k * 32 + q * 8;
    f32x4 xa = *(const f32x4*)xp;
    f32x4 xb = *(const f32x4*)(xp + 4);
    short8 af;
#pragma unroll
    for (int e = 0; e < 4; e++) { af[e] = (short)f2bf(xa[e]); af[4 + e] = (short)f2bf(xb[e]); }
#pragma unroll
    for (int dg = 0; dg < 8; dg++) {
      short8 bf = *(const short8*)(Wb1 + (dg * 16 + l15) * 128 + k * 32 + q * 8);
      acc[dg] = __builtin_amdgcn_mfma_f32_16x16x32_bf16(af, bf, acc[dg], 0, 0, 0);
    }
  }
#pragma unroll
  for (int dg = 0; dg < 8; dg++) {
    float bias = Wbias[dg * 16 + l15];
#pragma unroll
    for (int r = 0; r < 4; r++)
      hsm[w][q * 4 + r][dg * 16 + l15] = f2bf(acc[dg][r] + bias);
  }
  __syncthreads();
  f32x4 acc2[8];
#pragma unroll
  for (int dg = 0; dg < 8; dg++) acc2[dg] = (f32x4){0.f, 0.f, 0.f, 0.f};
#pragma unroll
  for (int k = 0; k < 4; k++) {
    short8 af = *(short8*)&hsm[w][l15][k * 32 + q * 8];
#pragma unroll
    for (int dg = 0; dg < 8; dg++) {
      short8 bf = *(const short8*)(Abt + (dg * 16 + l15) * 128 + k * 32 + q * 8);
      acc2[dg] = __builtin_amdgcn_mfma_f32_16x16x32_bf16(af, bf, acc2[dg], 0, 0, 0);
    }
  }
#pragma unroll
  for (int dg = 0; dg < 8; dg++)
#pragma unroll
    for (int r = 0; r < 4; r++)
      hasm[w][q * 4 + r][dg * 16 + l15] = f2bf(acc2[dg][r]);
  __syncthreads();
#pragma unroll
  for (int it = 0; it < 8; it++) {
    int idx = it * 64 + lane;
    int row = idx >> 5, c = idx & 31;
    short8 v = (c < 16) ? *(short8*)&hasm[w][row][c * 8]
                        : *(short8*)&hsm[w][row][(c - 16) * 8];
    *(short8*)(cat + ((r0 + row) << 8) + c * 8) = v;
  }
}

// ---------- k2: E once; s[k] += mask*exp(E); P_un packed-pair bf16 ----------
// grid (N/128, 8, B); 4 waves; wave w owns k-cols [kbase+w*32, +32),
// lane pair cols kc+2*l15, kc+2*l15+1. LDS-staged cat tile; j-span 256.
__global__ __launch_bounds__(256, 4) void k2(const unsigned short* __restrict__ cat,
                                             const unsigned int* __restrict__ bits,
                                             unsigned short* __restrict__ pun,
                                             float* __restrict__ s_out) {
  __shared__ unsigned short cj[64 * 256];  // 32 KB, XOR-swizzled chunks
  const int t = threadIdx.x, w = t >> 6, lane = t & 63;
  const int q = lane >> 4, l15 = lane & 15;
  const int b = blockIdx.z;
  const int kbase = blockIdx.x * 128;
  const int j0b = blockIdx.y * 256;
  const size_t bN = (size_t)b * N_;
  const unsigned short* catp = cat + (bN << 8);
  const int kc = kbase + w * 32;
  const int kw = kc >> 5;
  short8 brg[2][8];
#pragma unroll
  for (int p = 0; p < 2; p++) {
    int krow = kc + 2 * l15 + p;
#pragma unroll
    for (int m = 0; m < 8; m++)
      brg[p][m] = *(const short8*)(catp + (((size_t)krow) << 8) +
                                   ((((m * 4 + q) + 16) & 31) * 8));
  }
  float acc0 = 0.f, acc1 = 0.f;
  for (int jt = 0; jt < 4; jt++) {
    const int j0 = j0b + jt * 64;
#pragma unroll
    for (int it = 0; it < 8; it++) {
      int sI = it * 256 + t;
      int row = sI >> 5, c = sI & 31;
      GLL(catp + (((size_t)(j0 + row)) << 8) + (c ^ (row & 7)) * 8,
          (char*)cj + sI * 16);
    }
    __syncthreads();
#pragma unroll
    for (int jsub = 0; jsub < 4; jsub++) {
      const int row = jsub * 16 + l15;
      short8 afr[8];
#pragma unroll
      for (int m = 0; m < 8; m++)
        afr[m] = *(short8*)(cj + row * 256 + (((m * 4 + q) ^ (l15 & 7)) * 8));
      f32x4 e0 = {0.f, 0.f, 0.f, 0.f}, e1 = {0.f, 0.f, 0.f, 0.f};
#pragma unroll
      for (int m = 0; m < 8; m++) {
        e0 = __builtin_amdgcn_mfma_f32_16x16x32_bf16(afr[m], brg[0][m], e0, 0, 0, 0);
        e1 = __builtin_amdgcn_mfma_f32_16x16x32_bf16(afr[m], brg[1][m], e1, 0, 0, 0);
      }
#pragma unroll
      for (int r = 0; r < 4; r++) {
        int jrow = j0 + jsub * 16 + q * 4 + r;
        unsigned int mb = bits[(bN + jrow) * 64 + kw];
        float x0 = ((mb >> (2 * l15)) & 1u) ? __expf(fminf(e0[r], 60.f)) : 0.f;
        float x1 = ((mb >> (2 * l15 + 1)) & 1u) ? __expf(fminf(e1[r], 60.f)) : 0.f;
        acc0 += x0; acc1 += x1;
        unsigned int pk = (unsigned int)f2bf(x0) | ((unsigned int)f2bf(x1) << 16);
        *(unsigned int*)(pun + ((bN + jrow) << 11) + kc + 2 * l15) = pk;
      }
    }
    __syncthreads();
  }
  acc0 += __shfl_xor(acc0, 16, 64); acc0 += __shfl_xor(acc0, 32, 64);
  acc1 += __shfl_xor(acc1, 16, 64); acc1 += __shfl_xor(acc1, 32, 64);
  if (lane < 16) {
    atomicAdd(&s_out[bN + kc + 2 * lane], acc0);
    atomicAdd(&s_out[bN + kc + 2 * lane + 1], acc1);
  }
}

// ---------- k1v: vt[b][d][j] = bf16(h[b][j][d] / s[j]) (proven) ----------
__global__ __launch_bounds__(256) void k1v(const unsigned short* __restrict__ cat,
                                           const float* __restrict__ s,
                                           unsigned short* __restrict__ vt) {
  __shared__ unsigned short tile[64][136];
  __shared__ float rsv[64];
  const int t = threadIdx.x;
  const int b = blockIdx.y;
  const int nbase = blockIdx.x * 64;
  if (t < 64) rsv[t] = 1.f / s[(size_t)b * N_ + nbase + t];
#pragma unroll
  for (int k = 0; k < 4; k++) {
    int sI = t + 256 * k;
    int row = sI >> 4, part = sI & 15;
    *(short8*)&tile[row][part * 8] =
        *(const short8*)(cat + (((size_t)(b * N_ + nbase + row)) << 8) + 128 + part * 8);
  }
  __syncthreads();
#pragma unroll
  for (int k = 0; k < 4; k++) {
    int sI = t + 256 * k;
    int dd = sI >> 3, part = sI & 7;
    unsigned short tmp[8];
#pragma unroll
    for (int j = 0; j < 8; j++) {
      int jj = part * 8 + j;
      tmp[j] = f2bf(bf2f(tile[jj][dd]) * rsv[jj]);
    }
    *(short8*)(vt + (((size_t)(b * 128 + dd)) << 11) + nbase + part * 8) = *(short8*)tmp;
  }
}

// ---------- k3: partial h' = P_un[:, jspan] @ V'[jspan] (f32 raw sums) ----------
// grid (N/32, 4, B); 4 waves; wave w owns d-group [w*32, +32); j-tile 128;
// partial p covers j in [p*512, p*512+512). dst p=0 -> out, else parts.
__global__ __launch_bounds__(256) void k3(const unsigned short* __restrict__ pun,
                                          const unsigned short* __restrict__ vt,
                                          float* __restrict__ out,
                                          float* __restrict__ parts) {
  __shared__ char smem[40960];
  // [0,8192): A-tile P_un 32 x 128j   [8192,40960): B-tile vt 128d x 128j
  const int t = threadIdx.x, w = t >> 6, lane = t & 63;
  const int q = lane >> 4, l15 = lane & 15;
  const int b = blockIdx.z, i0 = blockIdx.x * 32, p = blockIdx.y;
  const size_t bN = (size_t)b * N_;
  unsigned short* pa = (unsigned short*)smem;
  unsigned short* vb = (unsigned short*)(smem + 8192);

  f32x4 acc[2][2];
#pragma unroll
  for (int ih = 0; ih < 2; ih++)
#pragma unroll
    for (int dh = 0; dh < 2; dh++) acc[ih][dh] = (f32x4){0.f, 0.f, 0.f, 0.f};

  for (int jt = 0; jt < 4; jt++) {
    const int j0 = p * 512 + jt * 128;
#pragma unroll
    for (int it = 0; it < 10; it++) {
      int sI = it * 256 + t;
      const unsigned short* g;
      if (sI < 512) {
        int row = sI >> 4, c = sI & 15;
        g = pun + (((size_t)(bN + i0 + row)) << 11) + j0 + ((c ^ (row & 7)) * 8);
      } else {
        int s2 = sI - 512;
        int dd = s2 >> 4, c = s2 & 15;
        g = vt + (((size_t)(b * 128 + dd)) << 11) + j0 + ((c ^ (dd & 7)) * 8);
      }
      GLL(g, smem + sI * 16);
    }
    __syncthreads();
#pragma unroll
    for (int ks = 0; ks < 4; ks++) {
      short8 af[2], bf[2];
#pragma unroll
      for (int ih = 0; ih < 2; ih++) {
        int m = ih * 16 + l15;
        af[ih] = *(short8*)(pa + m * 128 + (((ks * 4 + q) ^ (m & 7)) * 8));
      }
#pragma unroll
      for (int dh = 0; dh < 2; dh++) {
        int d = w * 32 + dh * 16 + l15;
        bf[dh] = *(short8*)(vb + d * 128 + (((ks * 4 + q) ^ (d & 7)) * 8));
      }
      acc[0][0] = __builtin_amdgcn_mfma_f32_16x16x32_bf16(af[0], bf[0], acc[0][0], 0, 0, 0);
      acc[0][1] = __builtin_amdgcn_mfma_f32_16x16x32_bf16(af[0], bf[1], acc[0][1], 0, 0, 0);
      acc[1][0] = __builtin_amdgcn_mfma_f32_16x16x32_bf16(af[1], bf[0], acc[1][0], 0, 0, 0);
      acc[1][1] = __builtin_amdgcn_mfma_f32_16x16x32_bf16(af[1], bf[1], acc[1][1], 0, 0, 0);
    }
    __syncthreads();
  }
  // write raw f32 partial via LDS for coalescing
  float* hs = (float*)smem;  // 32 x 132 f32 = 16896 B
#pragma unroll
  for (int ih = 0; ih < 2; ih++)
#pragma unroll
    for (int dh = 0; dh < 2; dh++)
#pragma unroll
      for (int r = 0; r < 4; r++)
        hs[(ih * 16 + q * 4 + r) * 132 + w * 32 + dh * 16 + l15] = acc[ih][dh][r];
  __syncthreads();
  float* dst = (p == 0) ? out : (parts + (size_t)(p - 1) * (PART_SZ / 4));
#pragma unroll
  for (int kk = 0; kk < 4; kk++) {
    int id = kk * 256 + t;
    int row = id >> 5, c4 = id & 31;
    *(f32x4*)(dst + (((size_t)(bN + i0 + row)) << 7) + c4 * 4) =
        *(f32x4*)(hs + row * 132 + c4 * 4);
  }
}

// ---------- k4: sum 4 partials, relu, gate, sigmoid, blend ----------
__global__ __launch_bounds__(256) void k4(const float* __restrict__ x,
                                          const float* __restrict__ gw,
                                          const float* __restrict__ gb,
                                          float* __restrict__ out,
                                          const float* __restrict__ parts) {
  const int t = threadIdx.x, w = t >> 6, lane = t & 63;
  const size_t row = (size_t)blockIdx.x * 4 + w;
  const size_t base = (row << 7) + lane * 2;
  float2 xv = *(const float2*)(x + base);
  float2 hv = *(const float2*)(out + base);
#pragma unroll
  for (int p = 1; p < 4; p++) {
    float2 pv = *(const float2*)(parts + (size_t)(p - 1) * (PART_SZ / 4) + base);
    hv.x += pv.x; hv.y += pv.y;
  }
  hv.x = fmaxf(hv.x, 0.f); hv.y = fmaxf(hv.y, 0.f);
  const int d = lane * 2;
  float z = gw[d] * xv.x + gw[d + 1] * xv.y + gw[128 + d] * hv.x + gw[129 + d] * hv.y;
  z += __shfl_xor(z, 1, 64);
  z += __shfl_xor(z, 2, 64);
  z += __shfl_xor(z, 4, 64);
  z += __shfl_xor(z, 8, 64);
  z += __shfl_xor(z, 16, 64);
  z += __shfl_xor(z, 32, 64);
  float c = 1.f / (1.f + __expf(-(z + gb[0])));
  float2 o;
  o.x = c * xv.x + (1.f - c) * hv.x;
  o.y = c * xv.y + (1.f - c) * hv.y;
  *(float2*)(out + base) = o;
}

extern "C" void kernel_launch(void* const* d_in, const int* in_sizes, int n_in,
                              void* d_out, int out_size, void* d_ws, size_t ws_size,
                              hipStream_t stream) {
  const float* x   = (const float*)d_in[0];
  const float* adj = (const float*)d_in[1];
  const float* Ww  = (const float*)d_in[2];
  const float* Wb  = (const float*)d_in[3];
  const float* A   = (const float*)d_in[4];
  const float* gw  = (const float*)d_in[5];
  const float* gb  = (const float*)d_in[6];
  float* out = (float*)d_out;
  char* ws = (char*)d_ws;

  unsigned short* cat = (unsigned short*)(ws + CAT_OFF);
  unsigned short* vt  = (unsigned short*)(ws + VT_OFF);
  unsigned short* pun = (unsigned short*)(ws + PUN_OFF);
  float* s  = (float*)(ws + S_OFF);
  unsigned short* Wb1 = (unsigned short*)(ws + WB_OFF);
  unsigned short* Abt = (unsigned short*)(ws + AT_OFF);
  unsigned int* bits  = (unsigned int*)(ws + BITS_OFF);
  float* parts = (float*)(ws + PART_OFF);

  hipMemsetAsync(s, 0, (size_t)B_ * N_ * sizeof(float), stream);
  k_cvt<<<1, 256, 0, stream>>>(Ww, A, Wb1, Abt);
  k_bits2<<<(B_ * N_ * N_) / (256 * 32), 256, 0, stream>>>(adj, bits);
  k1<<<(B_ * N_) / 64, 256, 0, stream>>>(x, Wb1, Wb, Abt, cat);
  k2<<<dim3(N_ / 128, 8, B_), 256, 0, stream>>>(cat, bits, pun, s);
  k1v<<<dim3(N_ / 64, B_), 256, 0, stream>>>(cat, s, vt);
  k3<<<dim3(N_ / 32, 4, B_), 256, 0, stream>>>(pun, vt, out, parts);
  k4<<<B_ * N_ / 4, 256, 0, stream>>>(x, gw, gb, out, parts);
}

// Round 12
// 310.338 us; speedup vs baseline: 1.1300x; 1.1300x over previous
//
#include <hip/hip_runtime.h>

// GAT_gate: B=8, N=2048, D=128
// out = c*x + (1-c)*relu(att@h), att = colsoftmax(mask(hA h^T + h hA^T))*adj
// e small (|e|<~6) -> exp without max-subtraction (clamp 60).
// cat[n][0:128]=hA[n], cat[n][128:256]=h[n]; e[i,j] = cat[i] . catsw[j].
// R12 = R11 with the kA grid bug fixed: bits work is B*N^2/(256*32) = 4096
// blocks (R11 launched 8192 -> blocks 4096..8191 read adj OOB -> GPU fault).
// Changes under test (vs R9 = 309us best):
//  (1) k3: j-loop PHASE STAGGER by (blockIdx.x&3)*4 (anti-lockstep at 2/CU).
//  (2) kA: bits + k1 merged (branch on blockIdx.x; overlaps HBM-bound bits
//      with compute-bound k1).
// k2/k1v/k3-arithmetic = R9 verbatim.

#define B_ 8
#define N_ 2048
#define D_ 128

#define BITS_BLOCKS 4096  // B*N*N / (256*32)

typedef __attribute__((ext_vector_type(8))) short short8;
typedef __attribute__((ext_vector_type(4))) float f32x4;

#define GLL(gp, lp) __builtin_amdgcn_global_load_lds( \
    (__attribute__((address_space(1))) const unsigned int*)(gp), \
    (__attribute__((address_space(3))) unsigned int*)(lp), 16, 0, 0)

static __device__ __forceinline__ unsigned short f2bf(float f) {
  union { float f; unsigned int u; } v; v.f = f;
  unsigned int r = v.u + 0x7fffu + ((v.u >> 16) & 1u);
  return (unsigned short)(r >> 16);
}
static __device__ __forceinline__ float bf2f(unsigned short u) {
  union { unsigned int u; float f; } v; v.u = ((unsigned int)u) << 16;
  return v.f;
}

// ---- workspace layout (bytes) ----
#define CAT_OFF  ((size_t)0)         // bf16 cat [B][N][256]        8 MB
#define VT_OFF   ((size_t)8388608)   // bf16 V'^T [B][128][N]       4 MB
#define PUN_OFF  ((size_t)12582912)  // bf16 P_un [B][N][N]         67.1 MB
#define S_OFF    ((size_t)79691776)  // f32 colsum s [B][N]         64 KB
#define WB_OFF   ((size_t)79757312)  // bf16 W [128][128]           32 KB
#define AT_OFF   ((size_t)79790080)  // bf16 A^T [128][128]         32 KB
#define BITS_OFF ((size_t)79822848)  // adj bits [B][N][N/32]       4 MB

// ---------- prep: W -> bf16 (same layout), A -> bf16 transposed ----------
__global__ void k_cvt(const float* __restrict__ W, const float* __restrict__ A,
                      unsigned short* __restrict__ Wb1, unsigned short* __restrict__ Abt) {
  int t = threadIdx.x;
  for (int i = t; i < 128 * 128; i += 256) {
    Wb1[i] = f2bf(W[i]);
    Abt[(i & 127) * 128 + (i >> 7)] = f2bf(A[i]);
  }
}

// ---------- kA: fat kernel = bits (blocks 0..4095) + k1 (4096..4351) ----------
// bits: adj -> bitmask, 32 contiguous elems/thread.
// k1: h = x@W^T + b, hA = h@A via MFMA; write cat bf16 (R9-proven body).
__global__ __launch_bounds__(256) void kA(const float* __restrict__ adj,
                                          unsigned int* __restrict__ bits,
                                          const float* __restrict__ x,
                                          const unsigned short* __restrict__ Wb1,
                                          const float* __restrict__ Wbias,
                                          const unsigned short* __restrict__ Abt,
                                          unsigned short* __restrict__ cat) {
  __shared__ unsigned short hsm[4][16][136];   // 272 B rows, 16B-aligned
  __shared__ unsigned short hasm[4][16][136];
  if (blockIdx.x < BITS_BLOCKS) {
    // ---- bits branch ----
    size_t tid = (size_t)blockIdx.x * 256 + threadIdx.x;
    const float* p = adj + tid * 32;
    unsigned int m = 0;
#pragma unroll
    for (int i = 0; i < 8; i++) {
      f32x4 v = *(const f32x4*)(p + i * 4);
      m |= (v[0] > 0.f ? 1u : 0u) << (i * 4 + 0);
      m |= (v[1] > 0.f ? 1u : 0u) << (i * 4 + 1);
      m |= (v[2] > 0.f ? 1u : 0u) << (i * 4 + 2);
      m |= (v[3] > 0.f ? 1u : 0u) << (i * 4 + 3);
    }
    bits[tid] = m;
    return;
  }
  // ---- k1 branch (R9 body) ----
  const int t = threadIdx.x, w = t >> 6, lane = t & 63;
  const int q = lane >> 4, l15 = lane & 15;
  const size_t r0 = (size_t)(blockIdx.x - BITS_BLOCKS) * 64 + w * 16;

  f32x4 acc[8];
#pragma unroll
  for (int dg = 0; dg < 8; dg++) acc[dg] = (f32x4){0.f, 0.f, 0.f, 0.f};
#pragma unroll
  for (int k = 0; k < 4; k++) {
    const float* xp = x + (r0 + l15) * 128 + k * 32 + q * 8;
    f32x4 xa = *(const f32x4*)xp;
    f32x4 xb = *(const f32x4*)(xp + 4);
    short8 af;
#pragma unroll
    for (int e = 0; e < 4; e++) { af[e] = (short)f2bf(xa[e]); af[4 + e] = (short)f2bf(xb[e]); }
#pragma unroll
    for (int dg = 0; dg < 8; dg++) {
      short8 bf = *(const short8*)(Wb1 + (dg * 16 + l15) * 128 + k * 32 + q * 8);
      acc[dg] = __builtin_amdgcn_mfma_f32_16x16x32_bf16(af, bf, acc[dg], 0, 0, 0);
    }
  }
#pragma unroll
  for (int dg = 0; dg < 8; dg++) {
    float bias = Wbias[dg * 16 + l15];
#pragma unroll
    for (int r = 0; r < 4; r++)
      hsm[w][q * 4 + r][dg * 16 + l15] = f2bf(acc[dg][r] + bias);
  }
  __syncthreads();
  f32x4 acc2[8];
#pragma unroll
  for (int dg = 0; dg < 8; dg++) acc2[dg] = (f32x4){0.f, 0.f, 0.f, 0.f};
#pragma unroll
  for (int k = 0; k < 4; k++) {
    short8 af = *(short8*)&hsm[w][l15][k * 32 + q * 8];
#pragma unroll
    for (int dg = 0; dg < 8; dg++) {
      short8 bf = *(const short8*)(Abt + (dg * 16 + l15) * 128 + k * 32 + q * 8);
      acc2[dg] = __builtin_amdgcn_mfma_f32_16x16x32_bf16(af, bf, acc2[dg], 0, 0, 0);
    }
  }
#pragma unroll
  for (int dg = 0; dg < 8; dg++)
#pragma unroll
    for (int r = 0; r < 4; r++)
      hasm[w][q * 4 + r][dg * 16 + l15] = f2bf(acc2[dg][r]);
  __syncthreads();
#pragma unroll
  for (int it = 0; it < 8; it++) {
    int idx = it * 64 + lane;
    int row = idx >> 5, c = idx & 31;
    short8 v = (c < 16) ? *(short8*)&hasm[w][row][c * 8]
                        : *(short8*)&hsm[w][row][(c - 16) * 8];
    *(short8*)(cat + ((r0 + row) << 8) + c * 8) = v;
  }
}

// ---------- k2: E once; s[k] += mask*exp(E); P_un packed-pair bf16 (R9) ----------
// grid (N/128, 16, B); 4 waves; wave w owns k-cols [kbase+w*32, +32),
// lane pair cols kc+2*l15, kc+2*l15+1. LDS-staged cat tile, bits masking.
__global__ __launch_bounds__(256, 3) void k2(const unsigned short* __restrict__ cat,
                                             const unsigned int* __restrict__ bits,
                                             unsigned short* __restrict__ pun,
                                             float* __restrict__ s_out) {
  __shared__ unsigned short cj[64 * 256];  // 32 KB, XOR-swizzled chunks
  const int t = threadIdx.x, w = t >> 6, lane = t & 63;
  const int q = lane >> 4, l15 = lane & 15;
  const int b = blockIdx.z;
  const int kbase = blockIdx.x * 128;
  const int j0b = blockIdx.y * 128;
  const size_t bN = (size_t)b * N_;
  const unsigned short* catp = cat + (bN << 8);
  const int kc = kbase + w * 32;
  const int kw = kc >> 5;
  short8 brg[2][8];
#pragma unroll
  for (int p = 0; p < 2; p++) {
    int krow = kc + 2 * l15 + p;
#pragma unroll
    for (int m = 0; m < 8; m++)
      brg[p][m] = *(const short8*)(catp + (((size_t)krow) << 8) +
                                   ((((m * 4 + q) + 16) & 31) * 8));
  }
  float acc0 = 0.f, acc1 = 0.f;
  for (int jt = 0; jt < 2; jt++) {
    const int j0 = j0b + jt * 64;
#pragma unroll
    for (int it = 0; it < 8; it++) {
      int sI = it * 256 + t;
      int row = sI >> 5, c = sI & 31;
      GLL(catp + (((size_t)(j0 + row)) << 8) + (c ^ (row & 7)) * 8,
          (char*)cj + sI * 16);
    }
    __syncthreads();
#pragma unroll
    for (int jsub = 0; jsub < 4; jsub++) {
      const int row = jsub * 16 + l15;
      short8 afr[8];
#pragma unroll
      for (int m = 0; m < 8; m++)
        afr[m] = *(short8*)(cj + row * 256 + (((m * 4 + q) ^ (l15 & 7)) * 8));
      f32x4 e0 = {0.f, 0.f, 0.f, 0.f}, e1 = {0.f, 0.f, 0.f, 0.f};
#pragma unroll
      for (int m = 0; m < 8; m++) {
        e0 = __builtin_amdgcn_mfma_f32_16x16x32_bf16(afr[m], brg[0][m], e0, 0, 0, 0);
        e1 = __builtin_amdgcn_mfma_f32_16x16x32_bf16(afr[m], brg[1][m], e1, 0, 0, 0);
      }
#pragma unroll
      for (int r = 0; r < 4; r++) {
        int jrow = j0 + jsub * 16 + q * 4 + r;
        unsigned int mb = bits[(bN + jrow) * 64 + kw];
        float x0 = ((mb >> (2 * l15)) & 1u) ? __expf(fminf(e0[r], 60.f)) : 0.f;
        float x1 = ((mb >> (2 * l15 + 1)) & 1u) ? __expf(fminf(e1[r], 60.f)) : 0.f;
        acc0 += x0; acc1 += x1;
        unsigned int pk = (unsigned int)f2bf(x0) | ((unsigned int)f2bf(x1) << 16);
        *(unsigned int*)(pun + ((bN + jrow) << 11) + kc + 2 * l15) = pk;
      }
    }
    __syncthreads();
  }
  acc0 += __shfl_xor(acc0, 16, 64); acc0 += __shfl_xor(acc0, 32, 64);
  acc1 += __shfl_xor(acc1, 16, 64); acc1 += __shfl_xor(acc1, 32, 64);
  if (lane < 16) {
    atomicAdd(&s_out[bN + kc + 2 * lane], acc0);
    atomicAdd(&s_out[bN + kc + 2 * lane + 1], acc1);
  }
}

// ---------- k1v: vt[b][d][j] = bf16(h[b][j][d] / s[j]) (proven) ----------
__global__ __launch_bounds__(256) void k1v(const unsigned short* __restrict__ cat,
                                           const float* __restrict__ s,
                                           unsigned short* __restrict__ vt) {
  __shared__ unsigned short tile[64][136];
  __shared__ float rsv[64];
  const int t = threadIdx.x;
  const int b = blockIdx.y;
  const int nbase = blockIdx.x * 64;
  if (t < 64) rsv[t] = 1.f / s[(size_t)b * N_ + nbase + t];
#pragma unroll
  for (int k = 0; k < 4; k++) {
    int sI = t + 256 * k;
    int row = sI >> 4, part = sI & 15;
    *(short8*)&tile[row][part * 8] =
        *(const short8*)(cat + (((size_t)(b * N_ + nbase + row)) << 8) + 128 + part * 8);
  }
  __syncthreads();
#pragma unroll
  for (int k = 0; k < 4; k++) {
    int sI = t + 256 * k;
    int dd = sI >> 3, part = sI & 7;
    unsigned short tmp[8];
#pragma unroll
    for (int j = 0; j < 8; j++) {
      int jj = part * 8 + j;
      tmp[j] = f2bf(bf2f(tile[jj][dd]) * rsv[jj]);
    }
    *(short8*)(vt + (((size_t)(b * 128 + dd)) << 11) + nbase + part * 8) = *(short8*)tmp;
  }
}

// ---------- k3: h' = P_un @ V'; out = c*x + (1-c)*relu(h') ----------
// grid (N/32, B); 4 waves; wave w owns d-group [w*32, +32); j-tile 128.
// PHASE STAGGER: block starts its j-ring at (blockIdx.x & 3) * 4 so
// co-resident blocks interleave stage/compute phases (anti-lockstep).
__global__ __launch_bounds__(256) void k3(const unsigned short* __restrict__ pun,
                                          const unsigned short* __restrict__ vt,
                                          const float* __restrict__ x,
                                          const float* __restrict__ gw,
                                          const float* __restrict__ gb,
                                          float* __restrict__ out) {
  __shared__ char smem[40960];
  // [0,8192): A-tile P_un 32 x 128j   [8192,40960): B-tile vt 128d x 128j
  const int t = threadIdx.x, w = t >> 6, lane = t & 63;
  const int q = lane >> 4, l15 = lane & 15;
  const int b = blockIdx.y, i0 = blockIdx.x * 32;
  const size_t bN = (size_t)b * N_;
  unsigned short* pa = (unsigned short*)smem;
  unsigned short* vb = (unsigned short*)(smem + 8192);
  const int ph = (blockIdx.x & 3) * 4;

  f32x4 acc[2][2];
#pragma unroll
  for (int ih = 0; ih < 2; ih++)
#pragma unroll
    for (int dh = 0; dh < 2; dh++) acc[ih][dh] = (f32x4){0.f, 0.f, 0.f, 0.f};

  for (int jt0 = 0; jt0 < N_ / 128; jt0++) {
    const int jt = (jt0 + ph) & (N_ / 128 - 1);
    const int j0 = jt * 128;
#pragma unroll
    for (int it = 0; it < 10; it++) {
      int sI = it * 256 + t;
      const unsigned short* g;
      if (sI < 512) {
        int row = sI >> 4, c = sI & 15;
        g = pun + (((size_t)(bN + i0 + row)) << 11) + j0 + ((c ^ (row & 7)) * 8);
      } else {
        int s2 = sI - 512;
        int dd = s2 >> 4, c = s2 & 15;
        g = vt + (((size_t)(b * 128 + dd)) << 11) + j0 + ((c ^ (dd & 7)) * 8);
      }
      GLL(g, smem + sI * 16);
    }
    __syncthreads();
#pragma unroll
    for (int ks = 0; ks < 4; ks++) {
      short8 af[2], bf[2];
#pragma unroll
      for (int ih = 0; ih < 2; ih++) {
        int m = ih * 16 + l15;
        af[ih] = *(short8*)(pa + m * 128 + (((ks * 4 + q) ^ (m & 7)) * 8));
      }
#pragma unroll
      for (int dh = 0; dh < 2; dh++) {
        int d = w * 32 + dh * 16 + l15;
        bf[dh] = *(short8*)(vb + d * 128 + (((ks * 4 + q) ^ (d & 7)) * 8));
      }
      acc[0][0] = __builtin_amdgcn_mfma_f32_16x16x32_bf16(af[0], bf[0], acc[0][0], 0, 0, 0);
      acc[0][1] = __builtin_amdgcn_mfma_f32_16x16x32_bf16(af[0], bf[1], acc[0][1], 0, 0, 0);
      acc[1][0] = __builtin_amdgcn_mfma_f32_16x16x32_bf16(af[1], bf[0], acc[1][0], 0, 0, 0);
      acc[1][1] = __builtin_amdgcn_mfma_f32_16x16x32_bf16(af[1], bf[1], acc[1][1], 0, 0, 0);
    }
    __syncthreads();
  }
  // epilogue: relu -> LDS f32, gate, sigmoid, blend, store
  float* hs = (float*)smem;            // 32 x 132 f32 = 16896 B
  float* co = (float*)(smem + 16896);  // 32 f32
#pragma unroll
  for (int ih = 0; ih < 2; ih++)
#pragma unroll
    for (int dh = 0; dh < 2; dh++)
#pragma unroll
      for (int r = 0; r < 4; r++) {
        int row = ih * 16 + q * 4 + r;
        int d = w * 32 + dh * 16 + l15;
        hs[row * 132 + d] = fmaxf(acc[ih][dh][r], 0.f);
      }
  __syncthreads();
  {
    int grow = t >> 3, sub = t & 7;
    const float* xr = x + (((size_t)(bN + i0 + grow)) << 7);
    float z = 0.f;
#pragma unroll
    for (int k = 0; k < 16; k++) {
      int dd = sub + 8 * k;
      z += gw[dd] * xr[dd] + gw[128 + dd] * hs[grow * 132 + dd];
    }
    z += __shfl_xor(z, 1, 64);
    z += __shfl_xor(z, 2, 64);
    z += __shfl_xor(z, 4, 64);
    if (sub == 0) co[grow] = 1.f / (1.f + __expf(-(z + gb[0])));
  }
  __syncthreads();
#pragma unroll
  for (int kk = 0; kk < 4; kk++) {
    int id = kk * 256 + t;
    int row = id >> 5, c4 = id & 31;
    size_t g = (((size_t)(bN + i0 + row)) << 7) + c4 * 4;
    f32x4 xv = *(const f32x4*)(x + g);
    f32x4 hv = *(const f32x4*)(hs + row * 132 + c4 * 4);
    float cf = co[row];
    f32x4 o;
#pragma unroll
    for (int e = 0; e < 4; e++) o[e] = cf * xv[e] + (1.f - cf) * hv[e];
    *(f32x4*)(out + g) = o;
  }
}

extern "C" void kernel_launch(void* const* d_in, const int* in_sizes, int n_in,
                              void* d_out, int out_size, void* d_ws, size_t ws_size,
                              hipStream_t stream) {
  const float* x   = (const float*)d_in[0];
  const float* adj = (const float*)d_in[1];
  const float* Ww  = (const float*)d_in[2];
  const float* Wb  = (const float*)d_in[3];
  const float* A   = (const float*)d_in[4];
  const float* gw  = (const float*)d_in[5];
  const float* gb  = (const float*)d_in[6];
  float* out = (float*)d_out;
  char* ws = (char*)d_ws;

  unsigned short* cat = (unsigned short*)(ws + CAT_OFF);
  unsigned short* vt  = (unsigned short*)(ws + VT_OFF);
  unsigned short* pun = (unsigned short*)(ws + PUN_OFF);
  float* s  = (float*)(ws + S_OFF);
  unsigned short* Wb1 = (unsigned short*)(ws + WB_OFF);
  unsigned short* Abt = (unsigned short*)(ws + AT_OFF);
  unsigned int* bits  = (unsigned int*)(ws + BITS_OFF);

  hipMemsetAsync(s, 0, (size_t)B_ * N_ * sizeof(float), stream);
  k_cvt<<<1, 256, 0, stream>>>(Ww, A, Wb1, Abt);
  kA<<<BITS_BLOCKS + (B_ * N_) / 64, 256, 0, stream>>>(adj, bits, x, Wb1, Wb, Abt, cat);
  k2<<<dim3(N_ / 128, 16, B_), 256, 0, stream>>>(cat, bits, pun, s);
  k1v<<<dim3(N_ / 64, B_), 256, 0, stream>>>(cat, s, vt);
  k3<<<dim3(N_ / 32, B_), 256, 0, stream>>>(pun, vt, x, gw, gb, out);
}

// Round 13
// 309.181 us; speedup vs baseline: 1.1342x; 1.0037x over previous
//
#include <hip/hip_runtime.h>

// GAT_gate: B=8, N=2048, D=128
// out = c*x + (1-c)*relu(att@h), att = colsoftmax(mask(hA h^T + h hA^T))*adj
// e small (|e|<~6) -> exp without max-subtraction (clamp 60).
// cat[n][0:128]=hA[n], cat[n][128:256]=h[n]; e[i,j] = cat[i] . catsw[j].
// R13 = R12 + XCD BATCH PINNING: k2/k1v/k3 grids linearized 1-D with
// b = blockIdx.x & 7, so all blocks of batch b land on XCD b (round-robin
// workgroup->XCD heuristic). Then vt_b (4 MB) and cat_b (1 MB) stay resident
// in XCD b's private 4 MB L2 instead of thrashing across 8 XCDs / spilling
// to Infinity Cache. (R12: stagger + merge both neutral -> k3 is cache-
// capacity-bound, not occupancy/barrier-bound.) Zero numeric change.

#define B_ 8
#define N_ 2048
#define D_ 128

#define BITS_BLOCKS 4096  // B*N*N / (256*32)

typedef __attribute__((ext_vector_type(8))) short short8;
typedef __attribute__((ext_vector_type(4))) float f32x4;

#define GLL(gp, lp) __builtin_amdgcn_global_load_lds( \
    (__attribute__((address_space(1))) const unsigned int*)(gp), \
    (__attribute__((address_space(3))) unsigned int*)(lp), 16, 0, 0)

static __device__ __forceinline__ unsigned short f2bf(float f) {
  union { float f; unsigned int u; } v; v.f = f;
  unsigned int r = v.u + 0x7fffu + ((v.u >> 16) & 1u);
  return (unsigned short)(r >> 16);
}
static __device__ __forceinline__ float bf2f(unsigned short u) {
  union { unsigned int u; float f; } v; v.u = ((unsigned int)u) << 16;
  return v.f;
}

// ---- workspace layout (bytes) ----
#define CAT_OFF  ((size_t)0)         // bf16 cat [B][N][256]        8 MB
#define VT_OFF   ((size_t)8388608)   // bf16 V'^T [B][128][N]       4 MB
#define PUN_OFF  ((size_t)12582912)  // bf16 P_un [B][N][N]         67.1 MB
#define S_OFF    ((size_t)79691776)  // f32 colsum s [B][N]         64 KB
#define WB_OFF   ((size_t)79757312)  // bf16 W [128][128]           32 KB
#define AT_OFF   ((size_t)79790080)  // bf16 A^T [128][128]         32 KB
#define BITS_OFF ((size_t)79822848)  // adj bits [B][N][N/32]       4 MB

// ---------- prep: W -> bf16 (same layout), A -> bf16 transposed ----------
__global__ void k_cvt(const float* __restrict__ W, const float* __restrict__ A,
                      unsigned short* __restrict__ Wb1, unsigned short* __restrict__ Abt) {
  int t = threadIdx.x;
  for (int i = t; i < 128 * 128; i += 256) {
    Wb1[i] = f2bf(W[i]);
    Abt[(i & 127) * 128 + (i >> 7)] = f2bf(A[i]);
  }
}

// ---------- kA: fat kernel = bits (blocks 0..4095) + k1 (4096..4351) ----------
__global__ __launch_bounds__(256) void kA(const float* __restrict__ adj,
                                          unsigned int* __restrict__ bits,
                                          const float* __restrict__ x,
                                          const unsigned short* __restrict__ Wb1,
                                          const float* __restrict__ Wbias,
                                          const unsigned short* __restrict__ Abt,
                                          unsigned short* __restrict__ cat) {
  __shared__ unsigned short hsm[4][16][136];   // 272 B rows, 16B-aligned
  __shared__ unsigned short hasm[4][16][136];
  if (blockIdx.x < BITS_BLOCKS) {
    size_t tid = (size_t)blockIdx.x * 256 + threadIdx.x;
    const float* p = adj + tid * 32;
    unsigned int m = 0;
#pragma unroll
    for (int i = 0; i < 8; i++) {
      f32x4 v = *(const f32x4*)(p + i * 4);
      m |= (v[0] > 0.f ? 1u : 0u) << (i * 4 + 0);
      m |= (v[1] > 0.f ? 1u : 0u) << (i * 4 + 1);
      m |= (v[2] > 0.f ? 1u : 0u) << (i * 4 + 2);
      m |= (v[3] > 0.f ? 1u : 0u) << (i * 4 + 3);
    }
    bits[tid] = m;
    return;
  }
  const int t = threadIdx.x, w = t >> 6, lane = t & 63;
  const int q = lane >> 4, l15 = lane & 15;
  const size_t r0 = (size_t)(blockIdx.x - BITS_BLOCKS) * 64 + w * 16;

  f32x4 acc[8];
#pragma unroll
  for (int dg = 0; dg < 8; dg++) acc[dg] = (f32x4){0.f, 0.f, 0.f, 0.f};
#pragma unroll
  for (int k = 0; k < 4; k++) {
    const float* xp = x + (r0 + l15) * 128 + k * 32 + q * 8;
    f32x4 xa = *(const f32x4*)xp;
    f32x4 xb = *(const f32x4*)(xp + 4);
    short8 af;
#pragma unroll
    for (int e = 0; e < 4; e++) { af[e] = (short)f2bf(xa[e]); af[4 + e] = (short)f2bf(xb[e]); }
#pragma unroll
    for (int dg = 0; dg < 8; dg++) {
      short8 bf = *(const short8*)(Wb1 + (dg * 16 + l15) * 128 + k * 32 + q * 8);
      acc[dg] = __builtin_amdgcn_mfma_f32_16x16x32_bf16(af, bf, acc[dg], 0, 0, 0);
    }
  }
#pragma unroll
  for (int dg = 0; dg < 8; dg++) {
    float bias = Wbias[dg * 16 + l15];
#pragma unroll
    for (int r = 0; r < 4; r++)
      hsm[w][q * 4 + r][dg * 16 + l15] = f2bf(acc[dg][r] + bias);
  }
  __syncthreads();
  f32x4 acc2[8];
#pragma unroll
  for (int dg = 0; dg < 8; dg++) acc2[dg] = (f32x4){0.f, 0.f, 0.f, 0.f};
#pragma unroll
  for (int k = 0; k < 4; k++) {
    short8 af = *(short8*)&hsm[w][l15][k * 32 + q * 8];
#pragma unroll
    for (int dg = 0; dg < 8; dg++) {
      short8 bf = *(const short8*)(Abt + (dg * 16 + l15) * 128 + k * 32 + q * 8);
      acc2[dg] = __builtin_amdgcn_mfma_f32_16x16x32_bf16(af, bf, acc2[dg], 0, 0, 0);
    }
  }
#pragma unroll
  for (int dg = 0; dg < 8; dg++)
#pragma unroll
    for (int r = 0; r < 4; r++)
      hasm[w][q * 4 + r][dg * 16 + l15] = f2bf(acc2[dg][r]);
  __syncthreads();
#pragma unroll
  for (int it = 0; it < 8; it++) {
    int idx = it * 64 + lane;
    int row = idx >> 5, c = idx & 31;
    short8 v = (c < 16) ? *(short8*)&hasm[w][row][c * 8]
                        : *(short8*)&hsm[w][row][(c - 16) * 8];
    *(short8*)(cat + ((r0 + row) << 8) + c * 8) = v;
  }
}

// ---------- k2: E once; s[k] += mask*exp(E); P_un packed-pair bf16 ----------
// grid 2048 1-D, XCD-pinned: b = blk&7, kbase = ((blk>>3)&15)*128,
// j0b = (blk>>7)*128. 4 waves; wave w owns k-cols [kbase+w*32, +32).
__global__ __launch_bounds__(256, 3) void k2(const unsigned short* __restrict__ cat,
                                             const unsigned int* __restrict__ bits,
                                             unsigned short* __restrict__ pun,
                                             float* __restrict__ s_out) {
  __shared__ unsigned short cj[64 * 256];  // 32 KB, XOR-swizzled chunks
  const int t = threadIdx.x, w = t >> 6, lane = t & 63;
  const int q = lane >> 4, l15 = lane & 15;
  const int blk = blockIdx.x;
  const int b = blk & 7;
  const int rest = blk >> 3;
  const int kbase = (rest & 15) * 128;
  const int j0b = (rest >> 4) * 128;
  const size_t bN = (size_t)b * N_;
  const unsigned short* catp = cat + (bN << 8);
  const int kc = kbase + w * 32;
  const int kw = kc >> 5;
  short8 brg[2][8];
#pragma unroll
  for (int p = 0; p < 2; p++) {
    int krow = kc + 2 * l15 + p;
#pragma unroll
    for (int m = 0; m < 8; m++)
      brg[p][m] = *(const short8*)(catp + (((size_t)krow) << 8) +
                                   ((((m * 4 + q) + 16) & 31) * 8));
  }
  float acc0 = 0.f, acc1 = 0.f;
  for (int jt = 0; jt < 2; jt++) {
    const int j0 = j0b + jt * 64;
#pragma unroll
    for (int it = 0; it < 8; it++) {
      int sI = it * 256 + t;
      int row = sI >> 5, c = sI & 31;
      GLL(catp + (((size_t)(j0 + row)) << 8) + (c ^ (row & 7)) * 8,
          (char*)cj + sI * 16);
    }
    __syncthreads();
#pragma unroll
    for (int jsub = 0; jsub < 4; jsub++) {
      const int row = jsub * 16 + l15;
      short8 afr[8];
#pragma unroll
      for (int m = 0; m < 8; m++)
        afr[m] = *(short8*)(cj + row * 256 + (((m * 4 + q) ^ (l15 & 7)) * 8));
      f32x4 e0 = {0.f, 0.f, 0.f, 0.f}, e1 = {0.f, 0.f, 0.f, 0.f};
#pragma unroll
      for (int m = 0; m < 8; m++) {
        e0 = __builtin_amdgcn_mfma_f32_16x16x32_bf16(afr[m], brg[0][m], e0, 0, 0, 0);
        e1 = __builtin_amdgcn_mfma_f32_16x16x32_bf16(afr[m], brg[1][m], e1, 0, 0, 0);
      }
#pragma unroll
      for (int r = 0; r < 4; r++) {
        int jrow = j0 + jsub * 16 + q * 4 + r;
        unsigned int mb = bits[(bN + jrow) * 64 + kw];
        float x0 = ((mb >> (2 * l15)) & 1u) ? __expf(fminf(e0[r], 60.f)) : 0.f;
        float x1 = ((mb >> (2 * l15 + 1)) & 1u) ? __expf(fminf(e1[r], 60.f)) : 0.f;
        acc0 += x0; acc1 += x1;
        unsigned int pk = (unsigned int)f2bf(x0) | ((unsigned int)f2bf(x1) << 16);
        *(unsigned int*)(pun + ((bN + jrow) << 11) + kc + 2 * l15) = pk;
      }
    }
    __syncthreads();
  }
  acc0 += __shfl_xor(acc0, 16, 64); acc0 += __shfl_xor(acc0, 32, 64);
  acc1 += __shfl_xor(acc1, 16, 64); acc1 += __shfl_xor(acc1, 32, 64);
  if (lane < 16) {
    atomicAdd(&s_out[bN + kc + 2 * lane], acc0);
    atomicAdd(&s_out[bN + kc + 2 * lane + 1], acc1);
  }
}

// ---------- k1v: vt[b][d][j] = bf16(h[b][j][d] / s[j]) ----------
// grid 256 1-D, XCD-pinned: b = blk&7, nbase = (blk>>3)*64.
__global__ __launch_bounds__(256) void k1v(const unsigned short* __restrict__ cat,
                                           const float* __restrict__ s,
                                           unsigned short* __restrict__ vt) {
  __shared__ unsigned short tile[64][136];
  __shared__ float rsv[64];
  const int t = threadIdx.x;
  const int blk = blockIdx.x;
  const int b = blk & 7;
  const int nbase = (blk >> 3) * 64;
  if (t < 64) rsv[t] = 1.f / s[(size_t)b * N_ + nbase + t];
#pragma unroll
  for (int k = 0; k < 4; k++) {
    int sI = t + 256 * k;
    int row = sI >> 4, part = sI & 15;
    *(short8*)&tile[row][part * 8] =
        *(const short8*)(cat + (((size_t)(b * N_ + nbase + row)) << 8) + 128 + part * 8);
  }
  __syncthreads();
#pragma unroll
  for (int k = 0; k < 4; k++) {
    int sI = t + 256 * k;
    int dd = sI >> 3, part = sI & 7;
    unsigned short tmp[8];
#pragma unroll
    for (int j = 0; j < 8; j++) {
      int jj = part * 8 + j;
      tmp[j] = f2bf(bf2f(tile[jj][dd]) * rsv[jj]);
    }
    *(short8*)(vt + (((size_t)(b * 128 + dd)) << 11) + nbase + part * 8) = *(short8*)tmp;
  }
}

// ---------- k3: h' = P_un @ V'; out = c*x + (1-c)*relu(h') ----------
// grid 512 1-D, XCD-pinned: b = blk&7 (vt_b stays in XCD b's L2),
// i0 = (blk>>3)*32. 4 waves; wave w owns d-group [w*32, +32); j-tile 128.
__global__ __launch_bounds__(256) void k3(const unsigned short* __restrict__ pun,
                                          const unsigned short* __restrict__ vt,
                                          const float* __restrict__ x,
                                          const float* __restrict__ gw,
                                          const float* __restrict__ gb,
                                          float* __restrict__ out) {
  __shared__ char smem[40960];
  // [0,8192): A-tile P_un 32 x 128j   [8192,40960): B-tile vt 128d x 128j
  const int t = threadIdx.x, w = t >> 6, lane = t & 63;
  const int q = lane >> 4, l15 = lane & 15;
  const int blk = blockIdx.x;
  const int b = blk & 7;
  const int i0 = (blk >> 3) * 32;
  const size_t bN = (size_t)b * N_;
  unsigned short* pa = (unsigned short*)smem;
  unsigned short* vb = (unsigned short*)(smem + 8192);
  const int ph = ((blk >> 3) & 3) * 4;

  f32x4 acc[2][2];
#pragma unroll
  for (int ih = 0; ih < 2; ih++)
#pragma unroll
    for (int dh = 0; dh < 2; dh++) acc[ih][dh] = (f32x4){0.f, 0.f, 0.f, 0.f};

  for (int jt0 = 0; jt0 < N_ / 128; jt0++) {
    const int jt = (jt0 + ph) & (N_ / 128 - 1);
    const int j0 = jt * 128;
#pragma unroll
    for (int it = 0; it < 10; it++) {
      int sI = it * 256 + t;
      const unsigned short* g;
      if (sI < 512) {
        int row = sI >> 4, c = sI & 15;
        g = pun + (((size_t)(bN + i0 + row)) << 11) + j0 + ((c ^ (row & 7)) * 8);
      } else {
        int s2 = sI - 512;
        int dd = s2 >> 4, c = s2 & 15;
        g = vt + (((size_t)(b * 128 + dd)) << 11) + j0 + ((c ^ (dd & 7)) * 8);
      }
      GLL(g, smem + sI * 16);
    }
    __syncthreads();
#pragma unroll
    for (int ks = 0; ks < 4; ks++) {
      short8 af[2], bf[2];
#pragma unroll
      for (int ih = 0; ih < 2; ih++) {
        int m = ih * 16 + l15;
        af[ih] = *(short8*)(pa + m * 128 + (((ks * 4 + q) ^ (m & 7)) * 8));
      }
#pragma unroll
      for (int dh = 0; dh < 2; dh++) {
        int d = w * 32 + dh * 16 + l15;
        bf[dh] = *(short8*)(vb + d * 128 + (((ks * 4 + q) ^ (d & 7)) * 8));
      }
      acc[0][0] = __builtin_amdgcn_mfma_f32_16x16x32_bf16(af[0], bf[0], acc[0][0], 0, 0, 0);
      acc[0][1] = __builtin_amdgcn_mfma_f32_16x16x32_bf16(af[0], bf[1], acc[0][1], 0, 0, 0);
      acc[1][0] = __builtin_amdgcn_mfma_f32_16x16x32_bf16(af[1], bf[0], acc[1][0], 0, 0, 0);
      acc[1][1] = __builtin_amdgcn_mfma_f32_16x16x32_bf16(af[1], bf[1], acc[1][1], 0, 0, 0);
    }
    __syncthreads();
  }
  // epilogue: relu -> LDS f32, gate, sigmoid, blend, store
  float* hs = (float*)smem;            // 32 x 132 f32 = 16896 B
  float* co = (float*)(smem + 16896);  // 32 f32
#pragma unroll
  for (int ih = 0; ih < 2; ih++)
#pragma unroll
    for (int dh = 0; dh < 2; dh++)
#pragma unroll
      for (int r = 0; r < 4; r++) {
        int row = ih * 16 + q * 4 + r;
        int d = w * 32 + dh * 16 + l15;
        hs[row * 132 + d] = fmaxf(acc[ih][dh][r], 0.f);
      }
  __syncthreads();
  {
    int grow = t >> 3, sub = t & 7;
    const float* xr = x + (((size_t)(bN + i0 + grow)) << 7);
    float z = 0.f;
#pragma unroll
    for (int k = 0; k < 16; k++) {
      int dd = sub + 8 * k;
      z += gw[dd] * xr[dd] + gw[128 + dd] * hs[grow * 132 + dd];
    }
    z += __shfl_xor(z, 1, 64);
    z += __shfl_xor(z, 2, 64);
    z += __shfl_xor(z, 4, 64);
    if (sub == 0) co[grow] = 1.f / (1.f + __expf(-(z + gb[0])));
  }
  __syncthreads();
#pragma unroll
  for (int kk = 0; kk < 4; kk++) {
    int id = kk * 256 + t;
    int row = id >> 5, c4 = id & 31;
    size_t g = (((size_t)(bN + i0 + row)) << 7) + c4 * 4;
    f32x4 xv = *(const f32x4*)(x + g);
    f32x4 hv = *(const f32x4*)(hs + row * 132 + c4 * 4);
    float cf = co[row];
    f32x4 o;
#pragma unroll
    for (int e = 0; e < 4; e++) o[e] = cf * xv[e] + (1.f - cf) * hv[e];
    *(f32x4*)(out + g) = o;
  }
}

extern "C" void kernel_launch(void* const* d_in, const int* in_sizes, int n_in,
                              void* d_out, int out_size, void* d_ws, size_t ws_size,
                              hipStream_t stream) {
  const float* x   = (const float*)d_in[0];
  const float* adj = (const float*)d_in[1];
  const float* Ww  = (const float*)d_in[2];
  const float* Wb  = (const float*)d_in[3];
  const float* A   = (const float*)d_in[4];
  const float* gw  = (const float*)d_in[5];
  const float* gb  = (const float*)d_in[6];
  float* out = (float*)d_out;
  char* ws = (char*)d_ws;

  unsigned short* cat = (unsigned short*)(ws + CAT_OFF);
  unsigned short* vt  = (unsigned short*)(ws + VT_OFF);
  unsigned short* pun = (unsigned short*)(ws + PUN_OFF);
  float* s  = (float*)(ws + S_OFF);
  unsigned short* Wb1 = (unsigned short*)(ws + WB_OFF);
  unsigned short* Abt = (unsigned short*)(ws + AT_OFF);
  unsigned int* bits  = (unsigned int*)(ws + BITS_OFF);

  hipMemsetAsync(s, 0, (size_t)B_ * N_ * sizeof(float), stream);
  k_cvt<<<1, 256, 0, stream>>>(Ww, A, Wb1, Abt);
  kA<<<BITS_BLOCKS + (B_ * N_) / 64, 256, 0, stream>>>(adj, bits, x, Wb1, Wb, Abt, cat);
  k2<<<16 * 16 * B_, 256, 0, stream>>>(cat, bits, pun, s);
  k1v<<<(N_ / 64) * B_, 256, 0, stream>>>(cat, s, vt);
  k3<<<(N_ / 32) * B_, 256, 0, stream>>>(pun, vt, x, gw, gb, out);
}